// Round 2
// baseline (154.141 us; speedup 1.0000x reference)
//
#include <hip/hip_runtime.h>
#include <math.h>

// SACConv: B=8, C1=C2=16, K=3, S=1, H=W=64, HDIM=16, N=C1*K*K=144, L=4096
// out[b,l,c] = sum_j h[l,j]*q[c,j] + q[c,16]
//   q[c,j]  = sum_o fc2_w[(c*144+o)*16+j] * p[l,o]
//   q[c,16] = sum_o fc2_b[c*144+o]        * p[l,o]
// Block = one image row (b,y): 64 locations, 256 threads (4 waves), 512 blocks.
// Main loop: lane = location, wave owns c-quad. Weights are wave-uniform ->
// fed via s_load (scalar pipe, SGPR operand of v_fmac), p via one ds_read_b32
// per o (lane-indexed, 2-way bank aliasing = free). LDS pipe nearly idle.

#define NPq 144

__global__ __launch_bounds__(256, 2) void sacconv_kernel(
    const float* __restrict__ x,
    const float* __restrict__ fc1_w,
    const float* __restrict__ fc1_b,
    const float* __restrict__ fc2_w,
    const float* __restrict__ fc2_b,
    float* __restrict__ out)
{
    __shared__ float P[NPq][64];     // patches [o][loc]     36864 B
    __shared__ float redA[4][64];    // reduction scratch
    __shared__ float redB[4][64];
    __shared__ float redC[4][64];
    __shared__ float redD[4][64];
    __shared__ float sb[64][8];      // per-loc broadcast stats
    __shared__ float Hl[64][17];     // h per location

    const int t   = threadIdx.x;
    const int blk = blockIdx.x;       // 512
    const int b   = blk >> 6;
    const int y   = blk & 63;

    const int loc = t & 63;
    const int grp = t >> 6;           // 0..3, o-range grp*36..grp*36+35

    // ---------- load patches: global -> VGPR cache + LDS, fused pass 1 ----------
    float v[36];
    {
        float s = 0.f, mx = -1e30f;
#pragma unroll
        for (int i = 0; i < 36; ++i) {
            const int c1 = grp * 4 + i / 9;
            const int ii = (i % 9) / 3;
            const int jj = i % 3;
            const int yy = y + ii - 1;
            const int xx = loc + jj - 1;
            float val = 0.f;
            if (yy >= 0 && yy < 64 && xx >= 0 && xx < 64)
                val = x[((b * 16 + c1) * 64 + yy) * 64 + xx];
            v[i] = val;
            P[grp * 36 + i][loc] = val;
            s += val;
            mx = fmaxf(mx, val);
        }
        redA[grp][loc] = s;
        redB[grp][loc] = mx;
    }
    __syncthreads();
    if (t < 64) {
        float s  = redA[0][t] + redA[1][t] + redA[2][t] + redA[3][t];
        float mx = fmaxf(fmaxf(redB[0][t], redB[1][t]), fmaxf(redB[2][t], redB[3][t]));
        sb[t][0] = s * (1.f / 144.f);
        sb[t][1] = mx;
    }
    __syncthreads();

    // ---------- pass 2: central moments 2,3,4 + sum exp (registers only) ----------
    {
        const float mu = sb[loc][0], mx = sb[loc][1];
        float m2 = 0.f, m3 = 0.f, m4 = 0.f, se = 0.f;
#pragma unroll
        for (int i = 0; i < 36; ++i) {
            const float d  = v[i] - mu;
            const float d2 = d * d;
            m2 += d2; m3 += d2 * d; m4 += d2 * d2;
            se += __expf(v[i] - mx);
        }
        redA[grp][loc] = m2; redB[grp][loc] = m3;
        redC[grp][loc] = m4; redD[grp][loc] = se;
    }
    __syncthreads();
    if (t < 64) {
        float m2 = redA[0][t] + redA[1][t] + redA[2][t] + redA[3][t];
        float m3 = redB[0][t] + redB[1][t] + redB[2][t] + redB[3][t];
        float m4 = redC[0][t] + redC[1][t] + redC[2][t] + redC[3][t];
        float Z  = redD[0][t] + redD[1][t] + redD[2][t] + redD[3][t];
        float var   = m2 * (1.f / 143.f);          // ddof=1
        float sigma = sqrtf(var) + 1e-6f;
        float is  = 1.f / sigma;
        float is2 = is * is;
        sb[t][2] = sigma;
        sb[t][3] = (m3 * (1.f / 144.f)) * is2 * is;         // skew
        sb[t][4] = (m4 * (1.f / 144.f)) * is2 * is2 - 3.f;  // kurtosis
        sb[t][5] = 1.f / Z;
    }
    __syncthreads();

    // ---------- pass 3: entropy partials (registers only) ----------
    {
        const float mx = sb[loc][1], invZ = sb[loc][5];
        float ent = 0.f;
#pragma unroll
        for (int i = 0; i < 36; ++i) {
            const float pr = __expf(v[i] - mx) * invZ;
            ent += pr * __logf(pr + 1e-6f);
        }
        redA[grp][loc] = ent;
    }
    __syncthreads();

    // ---------- h = relu(stats @ fc1_w^T + fc1_b) ----------
    {
        const float ent = -(redA[0][loc] + redA[1][loc] + redA[2][loc] + redA[3][loc]);
        const float s0 = sb[loc][0], s1 = sb[loc][2], s2 = sb[loc][3], s3 = sb[loc][4];
#pragma unroll
        for (int j0 = 0; j0 < 4; ++j0) {
            const int j = grp * 4 + j0;
            const float* wr = fc1_w + j * 5;
            float hv = s0 * wr[0] + s1 * wr[1] + s2 * wr[2] + s3 * wr[3]
                     + ent * wr[4] + fc1_b[j];
            Hl[loc][j] = fmaxf(hv, 0.f);
        }
    }
    __syncthreads();

    // ---------- main loop: lane = loc, wave owns c-quad; weights via SGPR ----------
    const int cbase = __builtin_amdgcn_readfirstlane(t >> 6) * 4;   // wave-uniform
    const int lane  = t & 63;

    float acc[4][17];
#pragma unroll
    for (int cc = 0; cc < 4; ++cc)
#pragma unroll
        for (int j = 0; j < 17; ++j) acc[cc][j] = 0.f;

    const float* __restrict__ w0 = fc2_w + (size_t)(cbase * NPq) * 16;
    const float* __restrict__ b0 = fc2_b + cbase * NPq;

#pragma unroll 4
    for (int o = 0; o < NPq; ++o) {
        const float pv = P[o][lane];          // ds_read_b32, 2-way alias -> free
#pragma unroll
        for (int cc = 0; cc < 4; ++cc) {
            const float* wr = w0 + (size_t)(cc * NPq + o) * 16;   // uniform -> s_load
#pragma unroll
            for (int j = 0; j < 16; ++j)
                acc[cc][j] = fmaf(pv, wr[j], acc[cc][j]);
            acc[cc][16] = fmaf(pv, b0[cc * NPq + o], acc[cc][16]);
        }
    }

    // ---------- epilogue: fold h, write out[b][c][l] ----------
    float hv[16];
#pragma unroll
    for (int j = 0; j < 16; ++j) hv[j] = Hl[lane][j];

#pragma unroll
    for (int cc = 0; cc < 4; ++cc) {
        float s = acc[cc][16];
#pragma unroll
        for (int j = 0; j < 16; ++j) s += hv[j] * acc[cc][j];
        out[(b * 16 + cbase + cc) * 4096 + y * 64 + lane] = s;
    }
}

extern "C" void kernel_launch(void* const* d_in, const int* in_sizes, int n_in,
                              void* d_out, int out_size, void* d_ws, size_t ws_size,
                              hipStream_t stream) {
    const float* x     = (const float*)d_in[0];
    const float* fc1_w = (const float*)d_in[1];
    const float* fc1_b = (const float*)d_in[2];
    const float* fc2_w = (const float*)d_in[3];
    const float* fc2_b = (const float*)d_in[4];
    float* out = (float*)d_out;

    sacconv_kernel<<<512, 256, 0, stream>>>(x, fc1_w, fc1_b, fc2_w, fc2_b, out);
}

// Round 3
// 81.131 us; speedup vs baseline: 1.8999x; 1.8999x over previous
//
#include <hip/hip_runtime.h>
#include <math.h>

// SACConv: B=8, C1=C2=16, K=3, S=1, H=W=64, HDIM=16, N=C1*K*K=144, L=4096
//
// out[b,l,c] = Qb[l,c] + sum_j h[l,j]*Qw[l,c*16+j]
//   Q[32768 x 272] = P[32768 x 144] @ Wcat[144 x 272]   (bf16 MFMA, K padded to 160)
//   cols 0..255: (c,j) -> c*16+j from fc2_w ; cols 256..271: bias col c from fc2_b
//
// prep_bfrag: Wcat -> bf16 B-fragments in d_ws, MFMA lane order (coalesced 16B/lane).
// sacconv: block = one image row (64 locs, 4 waves). Stats in registers (as R2),
// patches written to LDS directly in A-fragment bf16 layout. Wave = m-tile,
// 17 n-tiles x 5 K-steps of v_mfma_f32_16x16x32_bf16, B prefetch distance 1.

typedef __attribute__((ext_vector_type(8))) short short8;
typedef __attribute__((ext_vector_type(4))) float float4v;

#define NPq 144

__device__ __forceinline__ unsigned short f2bf(float f) {
    unsigned int u = __builtin_bit_cast(unsigned int, f);
    u += 0x7fffu + ((u >> 16) & 1u);
    return (unsigned short)(u >> 16);
}
__device__ __forceinline__ float bf2f(unsigned short h) {
    unsigned int u = ((unsigned int)h) << 16;
    return __builtin_bit_cast(float, u);
}

// ---------- prep: B fragments ----------
// Bfrag[(t*5+s)*64 + lane] = 8 bf16 of B[k = s*32+(lane>>4)*8+j][n = lane&15]
// t<16: B[k][n] = fc2_w[(t*144+k)*16+n]; t==16: fc2_b[n*144+k]; k>=144 -> 0
__global__ void prep_bfrag(const float* __restrict__ fc2_w,
                           const float* __restrict__ fc2_b,
                           unsigned short* __restrict__ Bfrag) {
    const int blk  = blockIdx.x;           // 85 = 17*5
    const int t    = blk / 5, s = blk % 5;
    const int lane = threadIdx.x;          // 64
    const int n    = lane & 15, q = lane >> 4;
    short8 v;
#pragma unroll
    for (int j = 0; j < 8; ++j) {
        const int k = s * 32 + q * 8 + j;
        float w = 0.f;
        if (k < NPq) w = (t < 16) ? fc2_w[(t * NPq + k) * 16 + n]
                                  : fc2_b[n * NPq + k];
        v[j] = (short)f2bf(w);
    }
    *(short8*)(Bfrag + (size_t)(blk * 64 + lane) * 8) = v;
}

// ---------- main ----------
__global__ __launch_bounds__(256, 2) void sacconv_kernel(
    const float* __restrict__ x,
    const float* __restrict__ fc1_w,
    const float* __restrict__ fc1_b,
    const unsigned short* __restrict__ Bfrag,
    float* __restrict__ out)
{
    // SH: phase 1 = A-fragments ushort[4][5][64][8] (10240 hw)
    //     phase 2 = Q dump ushort[64][280] (17920 hw)   -> 35840 B
    __shared__ unsigned short SH[64 * 280];
    __shared__ float redA[4][64];
    __shared__ float redB[4][64];
    __shared__ float redC[4][64];
    __shared__ float redD[4][64];
    __shared__ float sb[64][8];
    __shared__ float Hl[64][20];

    const int t   = threadIdx.x;
    const int blk = blockIdx.x;     // 512
    const int b   = blk >> 6;
    const int y   = blk & 63;

    const int loc = t & 63;
    const int grp = t >> 6;         // o-range grp*36 .. grp*36+35
    const int mt  = loc >> 4;       // m-tile of this thread's loc

    // ---------- pass 1: load patches -> regs + A-frag LDS, fused sum/max ----------
    float v[36];
    {
        const int thrbase = mt * 2560 + (loc & 15) * 8;   // halfword base in SH
        float s = 0.f, mx = -1e30f;
#pragma unroll
        for (int i = 0; i < 36; ++i) {
            const int c1 = grp * 4 + i / 9;
            const int ii = (i % 9) / 3;
            const int jj = i % 3;
            const int yy = y + ii - 1;
            const int xx = loc + jj - 1;
            float val = 0.f;
            if (yy >= 0 && yy < 64 && xx >= 0 && xx < 64)
                val = x[((b * 16 + c1) * 64 + yy) * 64 + xx];
            v[i] = val;
            const int o = grp * 36 + i;
            // A-frag slot: k=o -> s=o>>5, quad=(o>>3)&3, j=o&7
            SH[thrbase + (o >> 5) * 512 + ((o >> 3) & 3) * 128 + (o & 7)] = f2bf(val);
            s += val;
            mx = fmaxf(mx, val);
        }
        redA[grp][loc] = s;
        redB[grp][loc] = mx;
        // zero-fill A-frag K-pad (s=4, quads 2..3 i.e. k=144..159)
        const int idx = t & 63;
        unsigned short* zp = &SH[((grp * 5 + 4) * 64 + 32) * 8 + idx * 4];
        *(uint2*)zp = make_uint2(0u, 0u);
    }
    __syncthreads();
    if (t < 64) {
        float s  = redA[0][t] + redA[1][t] + redA[2][t] + redA[3][t];
        float mx = fmaxf(fmaxf(redB[0][t], redB[1][t]), fmaxf(redB[2][t], redB[3][t]));
        sb[t][0] = s * (1.f / 144.f);
        sb[t][1] = mx;
    }
    __syncthreads();

    // ---------- pass 2: central moments + sum exp ----------
    {
        const float mu = sb[loc][0], mx = sb[loc][1];
        float m2 = 0.f, m3 = 0.f, m4 = 0.f, se = 0.f;
#pragma unroll
        for (int i = 0; i < 36; ++i) {
            const float d  = v[i] - mu;
            const float d2 = d * d;
            m2 += d2; m3 += d2 * d; m4 += d2 * d2;
            se += __expf(v[i] - mx);
        }
        redA[grp][loc] = m2; redB[grp][loc] = m3;
        redC[grp][loc] = m4; redD[grp][loc] = se;
    }
    __syncthreads();
    if (t < 64) {
        float m2 = redA[0][t] + redA[1][t] + redA[2][t] + redA[3][t];
        float m3 = redB[0][t] + redB[1][t] + redB[2][t] + redB[3][t];
        float m4 = redC[0][t] + redC[1][t] + redC[2][t] + redC[3][t];
        float Z  = redD[0][t] + redD[1][t] + redD[2][t] + redD[3][t];
        float var   = m2 * (1.f / 143.f);          // ddof=1
        float sigma = sqrtf(var) + 1e-6f;
        float is  = 1.f / sigma;
        float is2 = is * is;
        sb[t][2] = sigma;
        sb[t][3] = (m3 * (1.f / 144.f)) * is2 * is;
        sb[t][4] = (m4 * (1.f / 144.f)) * is2 * is2 - 3.f;
        sb[t][5] = 1.f / Z;
    }
    __syncthreads();

    // ---------- pass 3: entropy ----------
    {
        const float mx = sb[loc][1], invZ = sb[loc][5];
        float ent = 0.f;
#pragma unroll
        for (int i = 0; i < 36; ++i) {
            const float pr = __expf(v[i] - mx) * invZ;
            ent += pr * __logf(pr + 1e-6f);
        }
        redA[grp][loc] = ent;
    }
    __syncthreads();

    // ---------- h = relu(stats @ fc1_w^T + fc1_b) ----------
    {
        const float ent = -(redA[0][loc] + redA[1][loc] + redA[2][loc] + redA[3][loc]);
        const float s0 = sb[loc][0], s1 = sb[loc][2], s2 = sb[loc][3], s3 = sb[loc][4];
#pragma unroll
        for (int j0 = 0; j0 < 4; ++j0) {
            const int j = grp * 4 + j0;
            const float* wr = fc1_w + j * 5;
            float hv = s0 * wr[0] + s1 * wr[1] + s2 * wr[2] + s3 * wr[3]
                     + ent * wr[4] + fc1_b[j];
            Hl[loc][j] = fmaxf(hv, 0.f);
        }
    }
    // no barrier needed here: Hl is read only after the post-MFMA barrier

    // ---------- MFMA main loop: wave = m-tile ----------
    const int w    = __builtin_amdgcn_readfirstlane(t >> 6);
    const int lane = t & 63;

    short8 af[5];
#pragma unroll
    for (int s = 0; s < 5; ++s)
        af[s] = *(const short8*)&SH[((w * 5 + s) * 64 + lane) * 8];

    float4v acc[17];
#pragma unroll
    for (int tt = 0; tt < 17; ++tt) acc[tt] = (float4v){0.f, 0.f, 0.f, 0.f};

    const short8* Bf = (const short8*)Bfrag;
    short8 cur[5], nxt[5];
#pragma unroll
    for (int s = 0; s < 5; ++s) cur[s] = Bf[s * 64 + lane];

#pragma unroll
    for (int tt = 0; tt < 17; ++tt) {
        if (tt < 16) {
#pragma unroll
            for (int s = 0; s < 5; ++s) nxt[s] = Bf[((tt + 1) * 5 + s) * 64 + lane];
        }
#pragma unroll
        for (int s = 0; s < 5; ++s)
            acc[tt] = __builtin_amdgcn_mfma_f32_16x16x32_bf16(af[s], cur[s], acc[tt], 0, 0, 0);
        if (tt < 16) {
#pragma unroll
            for (int s = 0; s < 5; ++s) cur[s] = nxt[s];
        }
    }

    // ---------- dump Q to LDS (bf16), aliasing dead A-frag space ----------
    __syncthreads();   // everyone done with af reads from SH
    {
        const int nn = lane & 15, qq = lane >> 4;
#pragma unroll
        for (int tt = 0; tt < 17; ++tt) {
            const int col = tt * 16 + nn;
#pragma unroll
            for (int r = 0; r < 4; ++r) {
                const int row = w * 16 + qq * 4 + r;   // C layout: col=lane&15, row=(lane>>4)*4+r
                SH[row * 280 + col] = f2bf(acc[tt][r]);
            }
        }
    }
    __syncthreads();

    // ---------- fold h, write out ----------
    {
        float hv[16];
#pragma unroll
        for (int j = 0; j < 16; ++j) hv[j] = Hl[loc][j];
        const int cg = w * 4;
#pragma unroll
        for (int cc = 0; cc < 4; ++cc) {
            const int c = cg + cc;
            const unsigned short* qr = &SH[loc * 280 + c * 16];
            short8 q0 = *(const short8*)qr;
            short8 q1 = *(const short8*)(qr + 8);
            float res = bf2f(SH[loc * 280 + 256 + c]);
#pragma unroll
            for (int j = 0; j < 8; ++j) res += hv[j]     * bf2f((unsigned short)q0[j]);
#pragma unroll
            for (int j = 0; j < 8; ++j) res += hv[8 + j] * bf2f((unsigned short)q1[j]);
            out[(b * 16 + c) * 4096 + y * 64 + loc] = res;
        }
    }
}

extern "C" void kernel_launch(void* const* d_in, const int* in_sizes, int n_in,
                              void* d_out, int out_size, void* d_ws, size_t ws_size,
                              hipStream_t stream) {
    const float* x     = (const float*)d_in[0];
    const float* fc1_w = (const float*)d_in[1];
    const float* fc1_b = (const float*)d_in[2];
    const float* fc2_w = (const float*)d_in[3];
    const float* fc2_b = (const float*)d_in[4];
    float* out = (float*)d_out;
    unsigned short* Bfrag = (unsigned short*)d_ws;   // 85*64*8*2 = 87040 B

    prep_bfrag<<<85, 64, 0, stream>>>(fc2_w, fc2_b, Bfrag);
    sacconv_kernel<<<512, 256, 0, stream>>>(x, fc1_w, fc1_b, Bfrag, out);
}